// Round 7
// baseline (1139.298 us; speedup 1.0000x reference)
//
#include <hip/hip_runtime.h>
#include <hip/hip_bf16.h>
#include <hip/hip_fp8.h>

#define TT 64   // timesteps
#define LL 64   // layers
#define BB 128  // batch
#define HH 64   // hidden
#define NP 32   // layer pairs (2 layers per WG)

typedef short v8s __attribute__((ext_vector_type(8)));   // 8 bf16 (MFMA A/B frag)
typedef float v4f __attribute__((ext_vector_type(4)));   // MFMA C/D frag

// ws layout (bytes):
//   prog  : int[2s][32p]                       @ 0     (16 KB reserved)
//   Wre   : ushort[LL][4w][4ga][4kf][64ln][8]  @ 16K   (4 MB) bf16 B-frags
//   hglob : ull[16slot][32p][2s][64b][16w]     @ +4MB  (8 MB) tagged fp8 words
//           low 32 = 4 x fp8-e4m3 (u = 4w..4w+3), high 32 = tag t
//   htop  : float[TT][HH][BB]                  @ +8MB  (2 MB)
//   partials: float[TT]
//
// 2 layers per WG: waves 0-3 = layer 2p (A), waves 4-7 = layer 2p+1 (B).
// A<->B exchange via LDS (hA), own-h via LDS (hA/hB). Only the pair->pair
// edge crosses WGs: B stores tagged fp8 words (tag rides with data, no fence);
// next WG's A polls all 16 words concurrently (success = 1 IC RTT).

__device__ __forceinline__ float sigm(float z)   {
    return __builtin_amdgcn_rcpf(1.f + __expf(-z));
}
__device__ __forceinline__ float tanh_f(float z) {
    return fmaf(-2.f, __builtin_amdgcn_rcpf(1.f + __expf(2.f * z)), 1.f);
}
__device__ __forceinline__ unsigned long long gload64(const unsigned long long* p) {
    return __hip_atomic_load(p, __ATOMIC_RELAXED, __HIP_MEMORY_SCOPE_AGENT);
}
__device__ __forceinline__ void gstore64(unsigned long long* p, unsigned long long v) {
    __hip_atomic_store(p, v, __ATOMIC_RELAXED, __HIP_MEMORY_SCOPE_AGENT);
}
__device__ __forceinline__ int fload(const int* p) {
    return __hip_atomic_load(p, __ATOMIC_RELAXED, __HIP_MEMORY_SCOPE_AGENT);
}
__device__ __forceinline__ void fstore(int* p, int v) {
    __hip_atomic_store(p, v, __ATOMIC_RELAXED, __HIP_MEMORY_SCOPE_AGENT);
}
__device__ __forceinline__ unsigned short f2bf(float f) {   // near-RNE truncation
    unsigned u = __float_as_uint(f);
    return (unsigned short)((u + 0x8000u) >> 16);
}

// B-frag packing: Wre[l][w][ga][kf][ln][j].
// B[k][n]: k = kf*32 + (ln>>4)*8 + j ; gcol = ga*64 + w*16 + (ln&15).
// k<64: below-h rows; k>=64: own-h rows. l==0: k==0 -> W0 x-row, 1..63 -> 0,
// k>=64 -> W0[k-63].  Also zero-inits prog (block 0).
__global__ __launch_bounds__(256, 1) void reorder_w(
    const float* __restrict__ W0, const float* __restrict__ Wl,
    unsigned short* __restrict__ Wre, int* __restrict__ prog)
{
    if (blockIdx.x == 0 && threadIdx.x < 64) prog[threadIdx.x] = 0;
    int idx = blockIdx.x * 256 + threadIdx.x;
    if (idx >= LL * 4 * 4 * 4 * 64 * 8) return;
    int j  = idx & 7;
    int ln = (idx >> 3) & 63;
    int kf = (idx >> 9) & 3;
    int ga = (idx >> 11) & 3;
    int w  = (idx >> 13) & 3;
    int l  = idx >> 15;
    int k    = kf * 32 + (ln >> 4) * 8 + j;
    int gcol = ga * 64 + w * 16 + (ln & 15);
    float v;
    if (l > 0)       v = Wl[((size_t)(l - 1) * 128 + k) * 256 + gcol];
    else if (k == 0) v = W0[gcol];
    else if (k < 64) v = 0.f;
    else             v = W0[(size_t)(k - 63) * 256 + gcol];
    Wre[idx] = f2bf(v);
}

__global__ __launch_bounds__(512, 2) void lstm_pipeline(
    const float* __restrict__ x,    // [B][T]
    const float* __restrict__ b0,   // [256]
    const float* __restrict__ bl,   // [63][256]
    const unsigned short* __restrict__ Wre,
    int* __restrict__ prog,                   // [2s][32p]
    unsigned long long* __restrict__ hglob,   // [16][32][2][64][16]
    float* __restrict__ htop)
{
    const int p   = blockIdx.x >> 1;
    const int s   = blockIdx.x & 1;
    const int tid = threadIdx.x;
    const int wv  = tid >> 6;
    const int la  = wv >> 2;         // 0 = layer 2p (A), 1 = layer 2p+1 (B)
    const int w   = wv & 3;          // u-stripe: units w*16 .. w*16+15
    const int ln  = tid & 63;
    const int lr  = ln & 15;
    const int qd  = ln >> 4;
    const int l   = 2 * p + la;

    __shared__ unsigned short hA[64 * 72];   // layer-A h(t), [b][u] bf16
    __shared__ unsigned short hB[64 * 72];   // layer-B h(t)
    __shared__ float xbuf[64 * 65];          // p==0 input staging

    for (int i = tid; i < 64 * 72; i += 512) { hA[i] = 0; hB[i] = 0; }
    if (p == 0) {
        for (int i = tid; i < 4096; i += 512)
            xbuf[(i >> 6) * 65 + (i & 63)] =
                x[(size_t)(s * 64 + (i >> 6)) * TT + (i & 63)];
    }

    // ---- persistent B fragments: 16 per wave (64 VGPRs) ----
    v8s bfr[16];
    const unsigned short* wb = Wre + (size_t)(l * 4 + w) * 8192;
#pragma unroll
    for (int f = 0; f < 16; ++f)
        bfr[f] = *(const v8s*)(wb + f * 512 + ln * 8);

    const float* bs = l ? (bl + (l - 1) * 256) : b0;
    float bias[4];
#pragma unroll
    for (int ga = 0; ga < 4; ++ga) bias[ga] = bs[ga * 64 + w * 16 + lr];

    float cst[16];                   // c-state: [mt][r]
#pragma unroll
    for (int i = 0; i < 16; ++i) cst[i] = 0.f;

    unsigned short* ownL = la ? hB : hA;
    __syncthreads();

    for (int k = 0; k <= TT; ++k) {
        const int t = la ? (k - 1) : k;          // this wave's timestep
        const bool active = la ? (t >= 0) : (t < TT);

        v4f acc[16];
#pragma unroll
        for (int i = 0; i < 16; ++i) acc[i] = (v4f){0.f, 0.f, 0.f, 0.f};

        unsigned int belowW[16];                 // A: 4 words x 4 mt payloads
        if (active && la == 0 && p > 0) {
            const unsigned long long* bp =
                hglob + (((size_t)(t & 15) * NP + (p - 1)) * 2 + s) * 1024;
            for (;;) {                           // all 16 polls in flight
                unsigned long long v[16];
#pragma unroll
                for (int mt = 0; mt < 4; ++mt) {
                    const unsigned long long* rp = bp + (size_t)(mt * 16 + lr) * 16;
                    v[mt * 4 + 0] = gload64(rp + qd * 2);
                    v[mt * 4 + 1] = gload64(rp + qd * 2 + 1);
                    v[mt * 4 + 2] = gload64(rp + 8 + qd * 2);
                    v[mt * 4 + 3] = gload64(rp + 8 + qd * 2 + 1);
                }
                unsigned int ok = 1;
#pragma unroll
                for (int i = 0; i < 16; ++i)
                    ok &= (unsigned int)((unsigned int)(v[i] >> 32) == (unsigned int)t);
                if (ok) {
#pragma unroll
                    for (int i = 0; i < 16; ++i) belowW[i] = (unsigned int)v[i];
                    break;
                }
            }
        }
        // slot-reuse gate (one B thread; 15-superbeat margin, rarely spins)
        if (active && la == 1 && tid == 511 && p < NP - 1)
            while (fload(&prog[s * NP + (p + 1)]) < t - 15) {}

        if (active) {
#pragma unroll
            for (int mt = 0; mt < 4; ++mt) {
                const int row = (mt * 16 + lr) * 72;
                v8s a2 = *(const v8s*)&ownL[row + qd * 8];        // own k=64..
                v8s a3 = *(const v8s*)&ownL[row + 32 + qd * 8];
                v8s a0, a1;
                if (la == 1) {                                    // below = hA (bf16)
                    a0 = *(const v8s*)&hA[row + qd * 8];
                    a1 = *(const v8s*)&hA[row + 32 + qd * 8];
                } else if (p > 0) {                               // below = fp8 words
#pragma unroll
                    for (int wi = 0; wi < 2; ++wi)
#pragma unroll
                        for (int bi = 0; bi < 4; ++bi) {
                            __hip_fp8_e4m3 f8;
                            f8.__x = (belowW[mt * 4 + wi] >> (8 * bi)) & 0xff;
                            a0[wi * 4 + bi] = (short)f2bf((float)f8);
                            f8.__x = (belowW[mt * 4 + 2 + wi] >> (8 * bi)) & 0xff;
                            a1[wi * 4 + bi] = (short)f2bf((float)f8);
                        }
                } else {                                          // below = x_t
                    a0 = (v8s){0, 0, 0, 0, 0, 0, 0, 0};
                    a1 = (v8s){0, 0, 0, 0, 0, 0, 0, 0};
                    if (qd == 0)
                        a0[0] = (short)f2bf(xbuf[(mt * 16 + lr) * 65 + t]);
                }
#pragma unroll
                for (int ga = 0; ga < 4; ++ga) {
                    v4f c = acc[mt * 4 + ga];
                    c = __builtin_amdgcn_mfma_f32_16x16x32_bf16(a2, bfr[ga * 4 + 2], c, 0, 0, 0);
                    c = __builtin_amdgcn_mfma_f32_16x16x32_bf16(a3, bfr[ga * 4 + 3], c, 0, 0, 0);
                    c = __builtin_amdgcn_mfma_f32_16x16x32_bf16(a0, bfr[ga * 4 + 0], c, 0, 0, 0);
                    c = __builtin_amdgcn_mfma_f32_16x16x32_bf16(a1, bfr[ga * 4 + 1], c, 0, 0, 0);
                    acc[mt * 4 + ga] = c;
                }
            }
        }
        __syncthreads();   // #1: all reads of hA/hB done

        if (active) {
            unsigned long long* dst = hglob +
                (((size_t)(t & 15) * NP + p) * 2 + s) * 1024;
#pragma unroll
            for (int mt = 0; mt < 4; ++mt) {
#pragma unroll
                for (int r = 0; r < 4; ++r) {
                    float zi = acc[mt * 4 + 0][r] + bias[0];
                    float zj = acc[mt * 4 + 1][r] + bias[1];
                    float zf = acc[mt * 4 + 2][r] + bias[2];
                    float zo = acc[mt * 4 + 3][r] + bias[3];
                    float c2 = cst[mt * 4 + r] * sigm(zf) + sigm(zi) * tanh_f(zj);
                    cst[mt * 4 + r] = c2;
                    float h2 = tanh_f(c2) * sigm(zo);
                    const int b = mt * 16 + qd * 4 + r;
                    ownL[b * 72 + w * 16 + lr] = f2bf(h2);
                    if (la == 1) {
                        if (p < NP - 1) {
                            __hip_fp8_e4m3 f8(h2);
                            unsigned int pk = ((unsigned int)f8.__x) << (8 * (lr & 3));
                            pk |= __shfl_xor(pk, 1);
                            pk |= __shfl_xor(pk, 2);
                            if ((lr & 3) == 0)
                                gstore64(dst + (size_t)b * 16 + w * 4 + (lr >> 2),
                                         (unsigned long long)pk |
                                         ((unsigned long long)(unsigned int)t << 32));
                        } else {
                            htop[((size_t)t * HH + (w * 16 + lr)) * BB + s * 64 + b] = h2;
                        }
                    }
                }
            }
            if (la == 0 && p > 0 && tid == 0)
                fstore(&prog[s * NP + p], t + 1);   // below t consumed
        }
        __syncthreads();   // #2: LDS writes visible for next superbeat
    }
}

__global__ __launch_bounds__(128, 1) void epilogue(
    const float* __restrict__ htop, const float* __restrict__ Wd,
    const float* __restrict__ bd, const float* __restrict__ labels,
    float* __restrict__ out, float* __restrict__ partials)
{
    int t = blockIdx.x, b = threadIdx.x;  // 64 blocks x 128 threads
    float s = 0.f;
#pragma unroll 4
    for (int h = 0; h < HH; ++h)
        s = fmaf(htop[(size_t)t * HH * BB + h * BB + b], Wd[t * HH + h], s);
    s += bd[t];
    s = fmaxf(s, 0.f);
    out[b * TT + t] = s;                  // pred [B][T][1]
    float d = labels[b * TT + t] - s;
    float e = d * d;
#pragma unroll
    for (int off = 32; off > 0; off >>= 1) e += __shfl_down(e, off, 64);
    __shared__ float ws2[2];
    if ((b & 63) == 0) ws2[b >> 6] = e;
    __syncthreads();
    if (b == 0) partials[t] = ws2[0] + ws2[1];
}

__global__ __launch_bounds__(64, 1) void finalize(const float* __restrict__ partials,
                                                  float* __restrict__ out) {
    int i = threadIdx.x;
    float v = partials[i];
#pragma unroll
    for (int off = 32; off > 0; off >>= 1) v += __shfl_down(v, off, 64);
    if (i == 0) out[BB * TT] = v * (1.f / (BB * TT));
}

extern "C" void kernel_launch(void* const* d_in, const int* in_sizes, int n_in,
                              void* d_out, int out_size, void* d_ws, size_t ws_size,
                              hipStream_t stream) {
    const float* x      = (const float*)d_in[0];
    const float* labels = (const float*)d_in[1];
    const float* W0     = (const float*)d_in[2];
    const float* b0     = (const float*)d_in[3];
    const float* Wl     = (const float*)d_in[4];
    const float* bl     = (const float*)d_in[5];
    const float* Wd     = (const float*)d_in[6];
    const float* bd     = (const float*)d_in[7];
    float* out = (float*)d_out;

    char* base = (char*)d_ws;
    int*                prog  = (int*)base;
    unsigned short*     Wre   = (unsigned short*)(base + 16384);
    unsigned long long* hglob = (unsigned long long*)(base + 16384 + 4194304);
    float*              htop  = (float*)(base + 16384 + 4194304 + 8388608);
    float*              partials = htop + (size_t)TT * HH * BB;

    reorder_w<<<8192, 256, 0, stream>>>(W0, Wl, Wre, prog);
    lstm_pipeline<<<64, 512, 0, stream>>>(x, b0, bl, Wre, prog, hglob, htop);
    epilogue<<<64, 128, 0, stream>>>(htop, Wd, bd, labels, out, partials);
    finalize<<<1, 64, 0, stream>>>(partials, out);
}

// Round 8
// 833.948 us; speedup vs baseline: 1.3662x; 1.3662x over previous
//
#include <hip/hip_runtime.h>
#include <hip/hip_bf16.h>
#include <hip/hip_fp8.h>

#define TT 64   // timesteps
#define LL 64   // layers
#define BB 128  // batch
#define HH 64   // hidden
#define NP 32   // layer pairs (2 layers per WG)

typedef short v8s __attribute__((ext_vector_type(8)));   // 8 bf16 (MFMA A/B frag)
typedef float v4f __attribute__((ext_vector_type(4)));   // MFMA C/D frag

// ws layout (bytes):
//   prog  : int[2s][32p]                       @ 0     (16 KB reserved)
//   Wre   : ushort[LL][4w][4ga][4kf][64ln][8]  @ 16K   (4 MB) bf16 B-frags
//   hglob : ull[16slot][32p][2s][64b][16w]     @ +4MB  (8 MB) tagged fp8 words
//           low 32 = 4 x fp8-e4m3 (u = 4w..4w+3), high 32 = tag t
//   htop  : float[TT][HH][BB]                  @ +8MB  (2 MB)
//   partials: float[TT]
//
// 2 layers per WG; waves 0-3 = layer 2p (A), waves 4-7 = layer 2p+1 (B).
// FIXED schedule (R7 bug): A and B both compute t=k in superbeat k.
// Order: A computes (poll below cross-WG) -> write hA[cur] -> barrier ->
// B computes (reads hA[cur] + hB[cur^1]) -> tagged store to next WG.
// ONE barrier per timestep; A's poll for t+1 overlaps B's compute of t.

__device__ __forceinline__ float sigm(float z)   {
    return __builtin_amdgcn_rcpf(1.f + __expf(-z));
}
__device__ __forceinline__ float tanh_f(float z) {
    return fmaf(-2.f, __builtin_amdgcn_rcpf(1.f + __expf(2.f * z)), 1.f);
}
__device__ __forceinline__ unsigned long long gload64(const unsigned long long* p) {
    return __hip_atomic_load(p, __ATOMIC_RELAXED, __HIP_MEMORY_SCOPE_AGENT);
}
__device__ __forceinline__ void gstore64(unsigned long long* p, unsigned long long v) {
    __hip_atomic_store(p, v, __ATOMIC_RELAXED, __HIP_MEMORY_SCOPE_AGENT);
}
__device__ __forceinline__ int fload(const int* p) {
    return __hip_atomic_load(p, __ATOMIC_RELAXED, __HIP_MEMORY_SCOPE_AGENT);
}
__device__ __forceinline__ void fstore(int* p, int v) {
    __hip_atomic_store(p, v, __ATOMIC_RELAXED, __HIP_MEMORY_SCOPE_AGENT);
}
__device__ __forceinline__ unsigned short f2bf(float f) {
    unsigned u = __float_as_uint(f);
    return (unsigned short)((u + 0x8000u) >> 16);
}

// B-frag packing (layout proven R7): Wre[l][w][ga][kf][ln][j].
// B[k][n]: k = kf*32 + (ln>>4)*8 + j ; gcol = ga*64 + w*16 + (ln&15).
// k<64: below-h rows; k>=64: own-h rows. l==0: k==0 -> W0 x-row, 1..63 -> 0,
// k>=64 -> W0[k-63].  Also zero-inits prog (block 0).
__global__ __launch_bounds__(256, 1) void reorder_w(
    const float* __restrict__ W0, const float* __restrict__ Wl,
    unsigned short* __restrict__ Wre, int* __restrict__ prog)
{
    if (blockIdx.x == 0 && threadIdx.x < 64) prog[threadIdx.x] = 0;
    int idx = blockIdx.x * 256 + threadIdx.x;
    if (idx >= LL * 4 * 4 * 4 * 64 * 8) return;
    int j  = idx & 7;
    int ln = (idx >> 3) & 63;
    int kf = (idx >> 9) & 3;
    int ga = (idx >> 11) & 3;
    int w  = (idx >> 13) & 3;
    int l  = idx >> 15;
    int k    = kf * 32 + (ln >> 4) * 8 + j;
    int gcol = ga * 64 + w * 16 + (ln & 15);
    float v;
    if (l > 0)       v = Wl[((size_t)(l - 1) * 128 + k) * 256 + gcol];
    else if (k == 0) v = W0[gcol];
    else if (k < 64) v = 0.f;
    else             v = W0[(size_t)(k - 63) * 256 + gcol];
    Wre[idx] = f2bf(v);
}

__global__ __launch_bounds__(512, 2) void lstm_pipeline(
    const float* __restrict__ x,    // [B][T]
    const float* __restrict__ b0,   // [256]
    const float* __restrict__ bl,   // [63][256]
    const unsigned short* __restrict__ Wre,
    int* __restrict__ prog,                   // [2s][32p]
    unsigned long long* __restrict__ hglob,   // [16][32][2][64][16]
    float* __restrict__ htop)
{
    const int p   = blockIdx.x >> 1;
    const int s   = blockIdx.x & 1;
    const int tid = threadIdx.x;
    const int wv  = tid >> 6;
    const int la  = wv >> 2;         // 0 = layer 2p (A), 1 = layer 2p+1 (B)
    const int w   = wv & 3;          // u-stripe: units w*16 .. w*16+15
    const int ln  = tid & 63;
    const int lr  = ln & 15;
    const int qd  = ln >> 4;
    const int l   = 2 * p + la;

    __shared__ unsigned short hA[2][64 * 72];  // layer-A h, double-buffered
    __shared__ unsigned short hB[2][64 * 72];  // layer-B h
    __shared__ float xbuf[64 * 65];            // p==0 input staging

    for (int i = tid; i < 64 * 72; i += 512) {
        hA[0][i] = 0; hA[1][i] = 0; hB[0][i] = 0; hB[1][i] = 0;
    }
    if (p == 0) {
        for (int i = tid; i < 4096; i += 512)
            xbuf[(i >> 6) * 65 + (i & 63)] =
                x[(size_t)(s * 64 + (i >> 6)) * TT + (i & 63)];
    }

    // ---- persistent B fragments: 16 per wave ----
    v8s bfr[16];
    const unsigned short* wb = Wre + (size_t)(l * 4 + w) * 8192;
#pragma unroll
    for (int f = 0; f < 16; ++f)
        bfr[f] = *(const v8s*)(wb + f * 512 + ln * 8);

    const float* bs = l ? (bl + (l - 1) * 256) : b0;
    float bias[4];
#pragma unroll
    for (int ga = 0; ga < 4; ++ga) bias[ga] = bs[ga * 64 + w * 16 + lr];

    float cst[16];                   // c-state: [mt][r]
#pragma unroll
    for (int i = 0; i < 16; ++i) cst[i] = 0.f;

    __syncthreads();

    for (int t = 0; t < TT; ++t) {
        const int cur = t & 1;

        if (la == 0) {
            // ================= A phase: layer 2p, timestep t =================
            unsigned int belowW[16];
            if (p > 0) {
                const unsigned long long* bp =
                    hglob + (((size_t)(t & 15) * NP + (p - 1)) * 2 + s) * 1024;
                for (;;) {                       // all 16 polls in flight
                    unsigned long long v[16];
#pragma unroll
                    for (int mt = 0; mt < 4; ++mt) {
                        const unsigned long long* rp = bp + (size_t)(mt * 16 + lr) * 16;
                        v[mt * 4 + 0] = gload64(rp + qd * 2);
                        v[mt * 4 + 1] = gload64(rp + qd * 2 + 1);
                        v[mt * 4 + 2] = gload64(rp + 8 + qd * 2);
                        v[mt * 4 + 3] = gload64(rp + 8 + qd * 2 + 1);
                    }
                    unsigned int ok = 1;
#pragma unroll
                    for (int i = 0; i < 16; ++i)
                        ok &= (unsigned int)((unsigned int)(v[i] >> 32) == (unsigned int)t);
                    if (ok) {
#pragma unroll
                        for (int i = 0; i < 16; ++i) belowW[i] = (unsigned int)v[i];
                        break;
                    }
                }
                if (tid == 0) fstore(&prog[s * NP + p], t + 1);  // consumed ack
            }

            v4f acc[16];
#pragma unroll
            for (int i = 0; i < 16; ++i) acc[i] = (v4f){0.f, 0.f, 0.f, 0.f};
#pragma unroll
            for (int mt = 0; mt < 4; ++mt) {
                const int row = (mt * 16 + lr) * 72;
                v8s a2 = *(const v8s*)&hA[cur ^ 1][row + qd * 8];       // own h(t-1)
                v8s a3 = *(const v8s*)&hA[cur ^ 1][row + 32 + qd * 8];
                v8s a0, a1;
                if (p > 0) {                                            // below = fp8
#pragma unroll
                    for (int wi = 0; wi < 2; ++wi)
#pragma unroll
                        for (int bi = 0; bi < 4; ++bi) {
                            __hip_fp8_e4m3 f8;
                            f8.__x = (belowW[mt * 4 + wi] >> (8 * bi)) & 0xff;
                            a0[wi * 4 + bi] = (short)f2bf((float)f8);
                            f8.__x = (belowW[mt * 4 + 2 + wi] >> (8 * bi)) & 0xff;
                            a1[wi * 4 + bi] = (short)f2bf((float)f8);
                        }
                } else {                                                // below = x_t
                    a0 = (v8s){0, 0, 0, 0, 0, 0, 0, 0};
                    a1 = (v8s){0, 0, 0, 0, 0, 0, 0, 0};
                    if (qd == 0)
                        a0[0] = (short)f2bf(xbuf[(mt * 16 + lr) * 65 + t]);
                }
#pragma unroll
                for (int ga = 0; ga < 4; ++ga) {
                    v4f c = acc[mt * 4 + ga];
                    c = __builtin_amdgcn_mfma_f32_16x16x32_bf16(a2, bfr[ga * 4 + 2], c, 0, 0, 0);
                    c = __builtin_amdgcn_mfma_f32_16x16x32_bf16(a3, bfr[ga * 4 + 3], c, 0, 0, 0);
                    c = __builtin_amdgcn_mfma_f32_16x16x32_bf16(a0, bfr[ga * 4 + 0], c, 0, 0, 0);
                    c = __builtin_amdgcn_mfma_f32_16x16x32_bf16(a1, bfr[ga * 4 + 1], c, 0, 0, 0);
                    acc[mt * 4 + ga] = c;
                }
            }
#pragma unroll
            for (int mt = 0; mt < 4; ++mt)
#pragma unroll
                for (int r = 0; r < 4; ++r) {
                    float zi = acc[mt * 4 + 0][r] + bias[0];
                    float zj = acc[mt * 4 + 1][r] + bias[1];
                    float zf = acc[mt * 4 + 2][r] + bias[2];
                    float zo = acc[mt * 4 + 3][r] + bias[3];
                    float c2 = cst[mt * 4 + r] * sigm(zf) + sigm(zi) * tanh_f(zj);
                    cst[mt * 4 + r] = c2;
                    float h2 = tanh_f(c2) * sigm(zo);
                    hA[cur][(mt * 16 + qd * 4 + r) * 72 + w * 16 + lr] = f2bf(h2);
                }
        }

        __syncthreads();   // hA[cur] (t) visible to B; B's prior reads done

        if (la == 1) {
            // ================= B phase: layer 2p+1, timestep t ===============
            // slot-reuse gate (wave-uniform poll; rarely binding)
            if (p < NP - 1 && t >= 15)
                while (fload(&prog[s * NP + (p + 1)]) < t - 14) {}

            v4f acc[16];
#pragma unroll
            for (int i = 0; i < 16; ++i) acc[i] = (v4f){0.f, 0.f, 0.f, 0.f};
#pragma unroll
            for (int mt = 0; mt < 4; ++mt) {
                const int row = (mt * 16 + lr) * 72;
                v8s a2 = *(const v8s*)&hB[cur ^ 1][row + qd * 8];       // own h(t-1)
                v8s a3 = *(const v8s*)&hB[cur ^ 1][row + 32 + qd * 8];
                v8s a0 = *(const v8s*)&hA[cur][row + qd * 8];           // below h(t)
                v8s a1 = *(const v8s*)&hA[cur][row + 32 + qd * 8];
#pragma unroll
                for (int ga = 0; ga < 4; ++ga) {
                    v4f c = acc[mt * 4 + ga];
                    c = __builtin_amdgcn_mfma_f32_16x16x32_bf16(a2, bfr[ga * 4 + 2], c, 0, 0, 0);
                    c = __builtin_amdgcn_mfma_f32_16x16x32_bf16(a3, bfr[ga * 4 + 3], c, 0, 0, 0);
                    c = __builtin_amdgcn_mfma_f32_16x16x32_bf16(a0, bfr[ga * 4 + 0], c, 0, 0, 0);
                    c = __builtin_amdgcn_mfma_f32_16x16x32_bf16(a1, bfr[ga * 4 + 1], c, 0, 0, 0);
                    acc[mt * 4 + ga] = c;
                }
            }
            unsigned long long* dst = hglob +
                (((size_t)(t & 15) * NP + p) * 2 + s) * 1024;
#pragma unroll
            for (int mt = 0; mt < 4; ++mt)
#pragma unroll
                for (int r = 0; r < 4; ++r) {
                    float zi = acc[mt * 4 + 0][r] + bias[0];
                    float zj = acc[mt * 4 + 1][r] + bias[1];
                    float zf = acc[mt * 4 + 2][r] + bias[2];
                    float zo = acc[mt * 4 + 3][r] + bias[3];
                    float c2 = cst[mt * 4 + r] * sigm(zf) + sigm(zi) * tanh_f(zj);
                    cst[mt * 4 + r] = c2;
                    float h2 = tanh_f(c2) * sigm(zo);
                    const int b = mt * 16 + qd * 4 + r;
                    hB[cur][b * 72 + w * 16 + lr] = f2bf(h2);
                    if (p < NP - 1) {
                        __hip_fp8_e4m3 f8(h2);
                        unsigned int pk = ((unsigned int)f8.__x) << (8 * (lr & 3));
                        pk |= __shfl_xor(pk, 1);
                        pk |= __shfl_xor(pk, 2);
                        if ((lr & 3) == 0)
                            gstore64(dst + (size_t)b * 16 + w * 4 + (lr >> 2),
                                     (unsigned long long)pk |
                                     ((unsigned long long)(unsigned int)t << 32));
                    } else {
                        htop[((size_t)t * HH + (w * 16 + lr)) * BB + s * 64 + b] = h2;
                    }
                }
        }
        // no second barrier: A(t+1) writes hA[cur^1], untouched by B(t) readers
    }
}

__global__ __launch_bounds__(128, 1) void epilogue(
    const float* __restrict__ htop, const float* __restrict__ Wd,
    const float* __restrict__ bd, const float* __restrict__ labels,
    float* __restrict__ out, float* __restrict__ partials)
{
    int t = blockIdx.x, b = threadIdx.x;  // 64 blocks x 128 threads
    float s = 0.f;
#pragma unroll 4
    for (int h = 0; h < HH; ++h)
        s = fmaf(htop[(size_t)t * HH * BB + h * BB + b], Wd[t * HH + h], s);
    s += bd[t];
    s = fmaxf(s, 0.f);
    out[b * TT + t] = s;                  // pred [B][T][1]
    float d = labels[b * TT + t] - s;
    float e = d * d;
#pragma unroll
    for (int off = 32; off > 0; off >>= 1) e += __shfl_down(e, off, 64);
    __shared__ float ws2[2];
    if ((b & 63) == 0) ws2[b >> 6] = e;
    __syncthreads();
    if (b == 0) partials[t] = ws2[0] + ws2[1];
}

__global__ __launch_bounds__(64, 1) void finalize(const float* __restrict__ partials,
                                                  float* __restrict__ out) {
    int i = threadIdx.x;
    float v = partials[i];
#pragma unroll
    for (int off = 32; off > 0; off >>= 1) v += __shfl_down(v, off, 64);
    if (i == 0) out[BB * TT] = v * (1.f / (BB * TT));
}

extern "C" void kernel_launch(void* const* d_in, const int* in_sizes, int n_in,
                              void* d_out, int out_size, void* d_ws, size_t ws_size,
                              hipStream_t stream) {
    const float* x      = (const float*)d_in[0];
    const float* labels = (const float*)d_in[1];
    const float* W0     = (const float*)d_in[2];
    const float* b0     = (const float*)d_in[3];
    const float* Wl     = (const float*)d_in[4];
    const float* bl     = (const float*)d_in[5];
    const float* Wd     = (const float*)d_in[6];
    const float* bd     = (const float*)d_in[7];
    float* out = (float*)d_out;

    char* base = (char*)d_ws;
    int*                prog  = (int*)base;
    unsigned short*     Wre   = (unsigned short*)(base + 16384);
    unsigned long long* hglob = (unsigned long long*)(base + 16384 + 4194304);
    float*              htop  = (float*)(base + 16384 + 4194304 + 8388608);
    float*              partials = htop + (size_t)TT * HH * BB;

    reorder_w<<<8192, 256, 0, stream>>>(W0, Wl, Wre, prog);
    lstm_pipeline<<<64, 512, 0, stream>>>(x, b0, bl, Wre, prog, hglob, htop);
    epilogue<<<64, 128, 0, stream>>>(htop, Wd, bd, labels, out, partials);
    finalize<<<1, 64, 0, stream>>>(partials, out);
}

// Round 9
// 524.544 us; speedup vs baseline: 2.1720x; 1.5899x over previous
//
#include <hip/hip_runtime.h>
#include <hip/hip_bf16.h>
#include <hip/hip_fp8.h>

#define TT 64   // timesteps
#define LL 64   // layers
#define BB 128  // batch
#define HH 64   // hidden
#define NP 32   // layer pairs (2 layers per WG)
#define SL 4    // batch slices (32 rows each)

typedef short v8s __attribute__((ext_vector_type(8)));   // 8 bf16 (MFMA A/B frag)
typedef float v4f __attribute__((ext_vector_type(4)));   // MFMA C/D frag

// ws layout (bytes):
//   prog  : int[SL][32p]                       @ 0     (16 KB reserved)
//   Wre   : ushort[LL][4w][4ga][4kf][64ln][8]  @ 16K   (4 MB) bf16 B-frags
//   hglob : ull[16slot][32p][SL][32b][16w]     @ +4MB  (8 MB) tagged fp8 words
//           low 32 = 4 x fp8-e4m3 (u = 4w..4w+3), high 32 = tag t
//   htop  : float[TT][HH][BB]                  @ +8MB  (2 MB)
//   partials: float[TT]
//
// 2 layers per WG, 4 independent batch-slice chains (batch rows never mix).
// Waves 0-3 = layer 2p (A), waves 4-7 = layer 2p+1 (B); both compute t=k in
// superbeat k (R8 schedule). One barrier per timestep. Cross-WG edge only
// pair->pair, via tagged fp8 words (tag rides with data -> poll IS the load).

__device__ __forceinline__ float sigm(float z)   {
    return __builtin_amdgcn_rcpf(1.f + __expf(-z));
}
__device__ __forceinline__ float tanh_f(float z) {
    return fmaf(-2.f, __builtin_amdgcn_rcpf(1.f + __expf(2.f * z)), 1.f);
}
__device__ __forceinline__ unsigned long long gload64(const unsigned long long* p) {
    return __hip_atomic_load(p, __ATOMIC_RELAXED, __HIP_MEMORY_SCOPE_AGENT);
}
__device__ __forceinline__ void gstore64(unsigned long long* p, unsigned long long v) {
    __hip_atomic_store(p, v, __ATOMIC_RELAXED, __HIP_MEMORY_SCOPE_AGENT);
}
__device__ __forceinline__ int fload(const int* p) {
    return __hip_atomic_load(p, __ATOMIC_RELAXED, __HIP_MEMORY_SCOPE_AGENT);
}
__device__ __forceinline__ void fstore(int* p, int v) {
    __hip_atomic_store(p, v, __ATOMIC_RELAXED, __HIP_MEMORY_SCOPE_AGENT);
}
__device__ __forceinline__ unsigned short f2bf(float f) {
    unsigned u = __float_as_uint(f);
    return (unsigned short)((u + 0x8000u) >> 16);
}

// B-frag packing (layout proven R7/R8): Wre[l][w][ga][kf][ln][j].
// B[k][n]: k = kf*32 + (ln>>4)*8 + j ; gcol = ga*64 + w*16 + (ln&15).
// k<64: below-h rows; k>=64: own-h rows. l==0: k==0 -> W0 x-row, 1..63 -> 0,
// k>=64 -> W0[k-63].  Also zero-inits prog (block 0).
__global__ __launch_bounds__(256, 1) void reorder_w(
    const float* __restrict__ W0, const float* __restrict__ Wl,
    unsigned short* __restrict__ Wre, int* __restrict__ prog)
{
    if (blockIdx.x == 0 && threadIdx.x < SL * NP) prog[threadIdx.x] = 0;
    int idx = blockIdx.x * 256 + threadIdx.x;
    if (idx >= LL * 4 * 4 * 4 * 64 * 8) return;
    int j  = idx & 7;
    int ln = (idx >> 3) & 63;
    int kf = (idx >> 9) & 3;
    int ga = (idx >> 11) & 3;
    int w  = (idx >> 13) & 3;
    int l  = idx >> 15;
    int k    = kf * 32 + (ln >> 4) * 8 + j;
    int gcol = ga * 64 + w * 16 + (ln & 15);
    float v;
    if (l > 0)       v = Wl[((size_t)(l - 1) * 128 + k) * 256 + gcol];
    else if (k == 0) v = W0[gcol];
    else if (k < 64) v = 0.f;
    else             v = W0[(size_t)(k - 63) * 256 + gcol];
    Wre[idx] = f2bf(v);
}

__global__ __launch_bounds__(512, 2) void lstm_pipeline(
    const float* __restrict__ x,    // [B][T]
    const float* __restrict__ b0,   // [256]
    const float* __restrict__ bl,   // [63][256]
    const unsigned short* __restrict__ Wre,
    int* __restrict__ prog,                   // [SL][32p]
    unsigned long long* __restrict__ hglob,   // [16][32][SL][32][16]
    float* __restrict__ htop)
{
    const int p   = blockIdx.x >> 2;
    const int s   = blockIdx.x & 3;  // batch slice: rows s*32 .. s*32+31
    const int tid = threadIdx.x;
    const int wv  = tid >> 6;
    const int la  = wv >> 2;         // 0 = layer 2p (A), 1 = layer 2p+1 (B)
    const int w   = wv & 3;          // u-stripe: units w*16 .. w*16+15
    const int ln  = tid & 63;
    const int lr  = ln & 15;
    const int qd  = ln >> 4;
    const int l   = 2 * p + la;

    __shared__ unsigned short hA[2][32 * 72];  // layer-A h (32 rows), dbuf
    __shared__ unsigned short hB[2][32 * 72];  // layer-B h
    __shared__ float xbuf[32 * 65];            // p==0 input staging

    for (int i = tid; i < 32 * 72; i += 512) {
        hA[0][i] = 0; hA[1][i] = 0; hB[0][i] = 0; hB[1][i] = 0;
    }
    if (p == 0) {
        for (int i = tid; i < 32 * 64; i += 512)
            xbuf[(i >> 6) * 65 + (i & 63)] =
                x[(size_t)(s * 32 + (i >> 6)) * TT + (i & 63)];
    }

    // ---- persistent B fragments: 16 per wave ----
    v8s bfr[16];
    const unsigned short* wb = Wre + (size_t)(l * 4 + w) * 8192;
#pragma unroll
    for (int f = 0; f < 16; ++f)
        bfr[f] = *(const v8s*)(wb + f * 512 + ln * 8);

    const float* bs = l ? (bl + (l - 1) * 256) : b0;
    float bias[4];
#pragma unroll
    for (int ga = 0; ga < 4; ++ga) bias[ga] = bs[ga * 64 + w * 16 + lr];

    float cst[8];                    // c-state: [mt][r], mt in {0,1}
#pragma unroll
    for (int i = 0; i < 8; ++i) cst[i] = 0.f;

    __syncthreads();

    for (int t = 0; t < TT; ++t) {
        const int cur = t & 1;

        if (la == 0) {
            // ================= A phase: layer 2p, timestep t =================
            unsigned int belowW[8];
            if (p > 0) {
                const unsigned long long* bp =
                    hglob + (((size_t)(t & 15) * NP + (p - 1)) * SL + s) * 512;
                for (;;) {                       // all 8 polls in flight
                    unsigned long long v[8];
#pragma unroll
                    for (int mt = 0; mt < 2; ++mt) {
                        const unsigned long long* rp = bp + (size_t)(mt * 16 + lr) * 16;
                        v[mt * 4 + 0] = gload64(rp + qd * 2);
                        v[mt * 4 + 1] = gload64(rp + qd * 2 + 1);
                        v[mt * 4 + 2] = gload64(rp + 8 + qd * 2);
                        v[mt * 4 + 3] = gload64(rp + 8 + qd * 2 + 1);
                    }
                    unsigned int ok = 1;
#pragma unroll
                    for (int i = 0; i < 8; ++i)
                        ok &= (unsigned int)((unsigned int)(v[i] >> 32) == (unsigned int)t);
                    if (ok) {
#pragma unroll
                        for (int i = 0; i < 8; ++i) belowW[i] = (unsigned int)v[i];
                        break;
                    }
                }
                if (tid == 0) fstore(&prog[s * NP + p], t + 1);  // consumed ack
            }

            v4f acc[8];
#pragma unroll
            for (int i = 0; i < 8; ++i) acc[i] = (v4f){0.f, 0.f, 0.f, 0.f};
#pragma unroll
            for (int mt = 0; mt < 2; ++mt) {
                const int row = (mt * 16 + lr) * 72;
                v8s a2 = *(const v8s*)&hA[cur ^ 1][row + qd * 8];       // own h(t-1)
                v8s a3 = *(const v8s*)&hA[cur ^ 1][row + 32 + qd * 8];
                v8s a0, a1;
                if (p > 0) {                                            // below = fp8
#pragma unroll
                    for (int wi = 0; wi < 2; ++wi)
#pragma unroll
                        for (int bi = 0; bi < 4; ++bi) {
                            __hip_fp8_e4m3 f8;
                            f8.__x = (belowW[mt * 4 + wi] >> (8 * bi)) & 0xff;
                            a0[wi * 4 + bi] = (short)f2bf((float)f8);
                            f8.__x = (belowW[mt * 4 + 2 + wi] >> (8 * bi)) & 0xff;
                            a1[wi * 4 + bi] = (short)f2bf((float)f8);
                        }
                } else {                                                // below = x_t
                    a0 = (v8s){0, 0, 0, 0, 0, 0, 0, 0};
                    a1 = (v8s){0, 0, 0, 0, 0, 0, 0, 0};
                    if (qd == 0)
                        a0[0] = (short)f2bf(xbuf[(mt * 16 + lr) * 65 + t]);
                }
#pragma unroll
                for (int ga = 0; ga < 4; ++ga) {
                    v4f c = acc[mt * 4 + ga];
                    c = __builtin_amdgcn_mfma_f32_16x16x32_bf16(a2, bfr[ga * 4 + 2], c, 0, 0, 0);
                    c = __builtin_amdgcn_mfma_f32_16x16x32_bf16(a3, bfr[ga * 4 + 3], c, 0, 0, 0);
                    c = __builtin_amdgcn_mfma_f32_16x16x32_bf16(a0, bfr[ga * 4 + 0], c, 0, 0, 0);
                    c = __builtin_amdgcn_mfma_f32_16x16x32_bf16(a1, bfr[ga * 4 + 1], c, 0, 0, 0);
                    acc[mt * 4 + ga] = c;
                }
            }
#pragma unroll
            for (int mt = 0; mt < 2; ++mt)
#pragma unroll
                for (int r = 0; r < 4; ++r) {
                    float zi = acc[mt * 4 + 0][r] + bias[0];
                    float zj = acc[mt * 4 + 1][r] + bias[1];
                    float zf = acc[mt * 4 + 2][r] + bias[2];
                    float zo = acc[mt * 4 + 3][r] + bias[3];
                    float c2 = cst[mt * 4 + r] * sigm(zf) + sigm(zi) * tanh_f(zj);
                    cst[mt * 4 + r] = c2;
                    float h2 = tanh_f(c2) * sigm(zo);
                    hA[cur][(mt * 16 + qd * 4 + r) * 72 + w * 16 + lr] = f2bf(h2);
                }
        }

        __syncthreads();   // hA[cur] (t) visible to B; B(t-1) LDS writes visible

        if (la == 1) {
            // ================= B phase: layer 2p+1, timestep t ===============
            int gate = 0;
            if (p < NP - 1 && t >= 15)
                gate = fload(&prog[s * NP + (p + 1)]);   // prefetch gate value

            v4f acc[8];
#pragma unroll
            for (int i = 0; i < 8; ++i) acc[i] = (v4f){0.f, 0.f, 0.f, 0.f};
#pragma unroll
            for (int mt = 0; mt < 2; ++mt) {
                const int row = (mt * 16 + lr) * 72;
                v8s a2 = *(const v8s*)&hB[cur ^ 1][row + qd * 8];       // own h(t-1)
                v8s a3 = *(const v8s*)&hB[cur ^ 1][row + 32 + qd * 8];
                v8s a0 = *(const v8s*)&hA[cur][row + qd * 8];           // below h(t)
                v8s a1 = *(const v8s*)&hA[cur][row + 32 + qd * 8];
#pragma unroll
                for (int ga = 0; ga < 4; ++ga) {
                    v4f c = acc[mt * 4 + ga];
                    c = __builtin_amdgcn_mfma_f32_16x16x32_bf16(a2, bfr[ga * 4 + 2], c, 0, 0, 0);
                    c = __builtin_amdgcn_mfma_f32_16x16x32_bf16(a3, bfr[ga * 4 + 3], c, 0, 0, 0);
                    c = __builtin_amdgcn_mfma_f32_16x16x32_bf16(a0, bfr[ga * 4 + 0], c, 0, 0, 0);
                    c = __builtin_amdgcn_mfma_f32_16x16x32_bf16(a1, bfr[ga * 4 + 1], c, 0, 0, 0);
                    acc[mt * 4 + ga] = c;
                }
            }
            // slot-reuse gate must pass before the tagged stores
            if (p < NP - 1 && t >= 15 && gate < t - 14)
                while (fload(&prog[s * NP + (p + 1)]) < t - 14) {}

            unsigned long long* dst = hglob +
                (((size_t)(t & 15) * NP + p) * SL + s) * 512;
#pragma unroll
            for (int mt = 0; mt < 2; ++mt)
#pragma unroll
                for (int r = 0; r < 4; ++r) {
                    float zi = acc[mt * 4 + 0][r] + bias[0];
                    float zj = acc[mt * 4 + 1][r] + bias[1];
                    float zf = acc[mt * 4 + 2][r] + bias[2];
                    float zo = acc[mt * 4 + 3][r] + bias[3];
                    float c2 = cst[mt * 4 + r] * sigm(zf) + sigm(zi) * tanh_f(zj);
                    cst[mt * 4 + r] = c2;
                    float h2 = tanh_f(c2) * sigm(zo);
                    const int b = mt * 16 + qd * 4 + r;
                    hB[cur][b * 72 + w * 16 + lr] = f2bf(h2);
                    if (p < NP - 1) {
                        __hip_fp8_e4m3 f8(h2);
                        unsigned int pk = ((unsigned int)f8.__x) << (8 * (lr & 3));
                        pk |= __shfl_xor(pk, 1);
                        pk |= __shfl_xor(pk, 2);
                        if ((lr & 3) == 0)
                            gstore64(dst + (size_t)b * 16 + w * 4 + (lr >> 2),
                                     (unsigned long long)pk |
                                     ((unsigned long long)(unsigned int)t << 32));
                    } else {
                        htop[((size_t)t * HH + (w * 16 + lr)) * BB + s * 32 + b] = h2;
                    }
                }
        }
        // no second barrier: A(t+1) writes hA[cur^1], disjoint from B(t) reads
    }
}

__global__ __launch_bounds__(128, 1) void epilogue(
    const float* __restrict__ htop, const float* __restrict__ Wd,
    const float* __restrict__ bd, const float* __restrict__ labels,
    float* __restrict__ out, float* __restrict__ partials)
{
    int t = blockIdx.x, b = threadIdx.x;  // 64 blocks x 128 threads
    float s = 0.f;
#pragma unroll 4
    for (int h = 0; h < HH; ++h)
        s = fmaf(htop[(size_t)t * HH * BB + h * BB + b], Wd[t * HH + h], s);
    s += bd[t];
    s = fmaxf(s, 0.f);
    out[b * TT + t] = s;                  // pred [B][T][1]
    float d = labels[b * TT + t] - s;
    float e = d * d;
#pragma unroll
    for (int off = 32; off > 0; off >>= 1) e += __shfl_down(e, off, 64);
    __shared__ float ws2[2];
    if ((b & 63) == 0) ws2[b >> 6] = e;
    __syncthreads();
    if (b == 0) partials[t] = ws2[0] + ws2[1];
}

__global__ __launch_bounds__(64, 1) void finalize(const float* __restrict__ partials,
                                                  float* __restrict__ out) {
    int i = threadIdx.x;
    float v = partials[i];
#pragma unroll
    for (int off = 32; off > 0; off >>= 1) v += __shfl_down(v, off, 64);
    if (i == 0) out[BB * TT] = v * (1.f / (BB * TT));
}

extern "C" void kernel_launch(void* const* d_in, const int* in_sizes, int n_in,
                              void* d_out, int out_size, void* d_ws, size_t ws_size,
                              hipStream_t stream) {
    const float* x      = (const float*)d_in[0];
    const float* labels = (const float*)d_in[1];
    const float* W0     = (const float*)d_in[2];
    const float* b0     = (const float*)d_in[3];
    const float* Wl     = (const float*)d_in[4];
    const float* bl     = (const float*)d_in[5];
    const float* Wd     = (const float*)d_in[6];
    const float* bd     = (const float*)d_in[7];
    float* out = (float*)d_out;

    char* base = (char*)d_ws;
    int*                prog  = (int*)base;
    unsigned short*     Wre   = (unsigned short*)(base + 16384);
    unsigned long long* hglob = (unsigned long long*)(base + 16384 + 4194304);
    float*              htop  = (float*)(base + 16384 + 4194304 + 8388608);
    float*              partials = htop + (size_t)TT * HH * BB;

    reorder_w<<<8192, 256, 0, stream>>>(W0, Wl, Wre, prog);
    lstm_pipeline<<<NP * SL, 512, 0, stream>>>(x, b0, bl, Wre, prog, hglob, htop);
    epilogue<<<64, 128, 0, stream>>>(htop, Wd, bd, labels, out, partials);
    finalize<<<1, 64, 0, stream>>>(partials, out);
}